// Round 2
// baseline (1111.575 us; speedup 1.0000x reference)
//
#include <hip/hip_runtime.h>
#include <stdint.h>

#define DIM   768
#define HEADS 12
#define NSP   1025      // spatial seq len (1 + 32*32)
#define VT_LD 1152      // padded row length of transposed V (>= 9*128)
#define PS_LD 152       // P/Q LDS leading dim (shorts): 304 B rows, 16B-aligned, quad-conflict-free

typedef __attribute__((ext_vector_type(8))) short short8;
typedef __attribute__((ext_vector_type(4))) float f32x4;
typedef unsigned short u16;
typedef unsigned int   u32;

__device__ __forceinline__ u16 f2bf(float v) {
  u32 u = __builtin_bit_cast(u32, v);
  u += 0x7fffu + ((u >> 16) & 1u);   // RNE
  return (u16)(u >> 16);
}
__device__ __forceinline__ float bf2f(u16 h) {
  u32 u = ((u32)h) << 16;
  return __builtin_bit_cast(float, u);
}

// ---------------------------------------------------------------- utility
__global__ __launch_bounds__(256) void zero_k(float* __restrict__ o, long n) {
  long i = (long)blockIdx.x * 256 + threadIdx.x;
  if (i < n) o[i] = 0.0f;
}

__global__ __launch_bounds__(256) void cvt_k(const float* __restrict__ src,
                                             u16* __restrict__ dst, long n) {
  long i = (long)blockIdx.x * 256 + threadIdx.x;
  if (i < n) dst[i] = f2bf(src[i]);
}

// ---------------------------------------------------------------- layernorm
__device__ __forceinline__ void ln_row(const float* __restrict__ src,
                                       u16* __restrict__ dst,
                                       const float* __restrict__ g,
                                       const float* __restrict__ b) {
  int tid = threadIdx.x;
  float v[3];
  float s = 0.f, ss = 0.f;
#pragma unroll
  for (int i = 0; i < 3; i++) {
    v[i] = src[tid + i * 256];
    s += v[i];
    ss += v[i] * v[i];
  }
  __shared__ float red[8];
#pragma unroll
  for (int m = 32; m; m >>= 1) {
    s  += __shfl_xor(s, m);
    ss += __shfl_xor(ss, m);
  }
  int wid = tid >> 6;
  if ((tid & 63) == 0) { red[wid] = s; red[4 + wid] = ss; }
  __syncthreads();
  s  = red[0] + red[1] + red[2] + red[3];
  ss = red[4] + red[5] + red[6] + red[7];
  float mean = s * (1.0f / 768.0f);
  float var  = ss * (1.0f / 768.0f) - mean * mean;
  float rs = rsqrtf(var + 1e-5f);
#pragma unroll
  for (int i = 0; i < 3; i++) {
    int c = tid + i * 256;
    dst[c] = f2bf((v[i] - mean) * rs * g[c] + b[c]);
  }
}

__global__ __launch_bounds__(256) void ln_xt_k(const float* __restrict__ x,
                                               const float* __restrict__ g,
                                               const float* __restrict__ b,
                                               u16* __restrict__ outb) {
  int q = blockIdx.x, bb = blockIdx.y;
  const float* src = x + ((long)bb * 4097 + 1 + q) * DIM;
  u16* dst = outb + ((long)bb * 4096 + q) * DIM;
  ln_row(src, dst, g, b);
}

__global__ __launch_bounds__(256) void ln_xs_k(const float* __restrict__ x,
                                               const float* __restrict__ xt,
                                               const float* __restrict__ g,
                                               const float* __restrict__ b,
                                               u16* __restrict__ outb) {
  int n = blockIdx.x, bt = blockIdx.y;
  int bb = bt >> 2, t = bt & 3;
  const float* src;
  if (n == 0) src = x + (long)bb * 4097 * DIM;
  else        src = xt + ((long)bb * 4096 + (long)(n - 1) * 4 + t) * DIM;
  u16* dst = outb + ((long)bt * NSP + n) * DIM;
  ln_row(src, dst, g, b);
}

__global__ __launch_bounds__(256) void ln2_k(const float* __restrict__ xo,
                                             const float* __restrict__ g,
                                             const float* __restrict__ b,
                                             u16* __restrict__ outb) {
  int n = blockIdx.x, bb = blockIdx.y;
  const float* src = xo + ((long)bb * 4097 + n) * DIM;
  u16* dst = outb + ((long)bb * 4097 + n) * DIM;
  ln_row(src, dst, g, b);
}

// ---------------------------------------------------------------- GEMM
// C[M,N] = act( scale*(A[M,K] @ W[N,K]^T) + bias ) + resid   (batched via z1)
struct GemmParams {
  const u16* A; long lda, sA1;
  const u16* B; long ldb;
  void* C;      long ldc, sC1;
  const float* bias;
  const float* resid; long ldr, sR1;
  float scale;
  int M, N, K;
};

template <bool OUTBF16, bool BIASV, bool RESID, bool GELU_>
__global__ __launch_bounds__(256) void gemm_k(GemmParams p) {
  __shared__ short As[128][40];
  __shared__ short Bs[128][40];
  int tid = threadIdx.x;
  int z1 = blockIdx.z;
  const u16* A = p.A + (long)z1 * p.sA1;
  const u16* B = p.B;
  int m0 = blockIdx.y * 128, n0 = blockIdx.x * 128;
  int wave = tid >> 6, lane = tid & 63;
  int quad = lane >> 4, lrow = lane & 15;
  int wm = (wave & 1) * 64, wn = (wave >> 1) * 64;

  f32x4 acc[4][4];
#pragma unroll
  for (int i = 0; i < 4; i++)
#pragma unroll
    for (int j = 0; j < 4; j++) acc[i][j] = (f32x4){0.f, 0.f, 0.f, 0.f};

  for (int k0 = 0; k0 < p.K; k0 += 32) {
#pragma unroll
    for (int s = 0; s < 2; s++) {
      int seg = tid + s * 256;             // 512 segments of 8 elems
      int row = seg >> 2, col = (seg & 3) << 3;
      {
        int gr = m0 + row;
        const u16* src = A + (long)gr * p.lda + k0 + col;
        short8 v;
        if (gr < p.M) {
          v = *(const short8*)src;
        } else {
          v = (short8){0,0,0,0,0,0,0,0};
        }
        *(short8*)&As[row][col] = v;
      }
      {
        int gc = n0 + row;
        const u16* src = B + (long)gc * p.ldb + k0 + col;
        short8 v;
        if (gc < p.N) {
          v = *(const short8*)src;
        } else {
          v = (short8){0,0,0,0,0,0,0,0};
        }
        *(short8*)&Bs[row][col] = v;
      }
    }
    __syncthreads();
    short8 af[4], bfr[4];
#pragma unroll
    for (int i = 0; i < 4; i++) af[i]  = *(const short8*)&As[wm + i * 16 + lrow][quad * 8];
#pragma unroll
    for (int j = 0; j < 4; j++) bfr[j] = *(const short8*)&Bs[wn + j * 16 + lrow][quad * 8];
#pragma unroll
    for (int i = 0; i < 4; i++)
#pragma unroll
      for (int j = 0; j < 4; j++)
        acc[i][j] = __builtin_amdgcn_mfma_f32_16x16x32_bf16(af[i], bfr[j], acc[i][j], 0, 0, 0);
    __syncthreads();
  }

  float* Cf = (float*)p.C;
  u16*   Ch = (u16*)p.C;
  long cbase = (long)z1 * p.sC1;
#pragma unroll
  for (int i = 0; i < 4; i++) {
    int rbase = m0 + wm + i * 16 + quad * 4;
#pragma unroll
    for (int j = 0; j < 4; j++) {
      int c = n0 + wn + j * 16 + lrow;
      if (c >= p.N) continue;
#pragma unroll
      for (int rr = 0; rr < 4; rr++) {
        int r = rbase + rr;
        if (r >= p.M) continue;
        float v = acc[i][j][rr] * p.scale;
        if (BIASV) v += p.bias[c];
        if (GELU_) v = 0.5f * v * (1.0f + erff(v * 0.70710678118654752f));
        if (RESID) v += p.resid[(long)z1 * p.sR1 + (long)r * p.ldr + c];
        long o = cbase + (long)r * p.ldc + c;
        if (OUTBF16) Ch[o] = f2bf(v);
        else         Cf[o] = v;
      }
    }
  }
}

// ---------------------------------------------------------------- temporal attention (T=4)
__global__ __launch_bounds__(64) void attn_t_k(const u16* __restrict__ qkv,
                                               u16* __restrict__ outb) {
  int h = blockIdx.x;      // 0..11
  int g = blockIdx.y;      // 0..2047
  int d = threadIdx.x;     // 0..63
  long base = (long)g * 4 * 2304 + h * 64 + d;
  float q[4], k[4], vv[4];
#pragma unroll
  for (int t = 0; t < 4; t++) {
    q[t]  = bf2f(qkv[base + (long)t * 2304]);
    k[t]  = bf2f(qkv[base + (long)t * 2304 + 768]);
    vv[t] = bf2f(qkv[base + (long)t * 2304 + 1536]);
  }
  float sc[4][4];
#pragma unroll
  for (int i = 0; i < 4; i++)
#pragma unroll
    for (int j = 0; j < 4; j++) {
      float pv = q[i] * k[j];
#pragma unroll
      for (int m = 32; m; m >>= 1) pv += __shfl_xor(pv, m);
      sc[i][j] = pv * 0.125f;
    }
#pragma unroll
  for (int i = 0; i < 4; i++) {
    float mx = fmaxf(fmaxf(sc[i][0], sc[i][1]), fmaxf(sc[i][2], sc[i][3]));
    float e0 = __expf(sc[i][0] - mx), e1 = __expf(sc[i][1] - mx);
    float e2 = __expf(sc[i][2] - mx), e3 = __expf(sc[i][3] - mx);
    float inv = 1.0f / (e0 + e1 + e2 + e3);
    float ov = (e0 * vv[0] + e1 * vv[1] + e2 * vv[2] + e3 * vv[3]) * inv;
    outb[((long)g * 4 + i) * DIM + h * 64 + d] = f2bf(ov);
  }
}

// ---------------------------------------------------------------- geometry tables
__global__ void geo_pre_k(const float* __restrict__ wg_w,
                          const float* __restrict__ wg_b,
                          float* __restrict__ sxsyc) {
  int t = threadIdx.x;
  if (t >= 384) return;
  int h = t >> 5, dd = t & 31;
  float dx = logf(fmaxf((float)dd * (1.0f / 33.0f), 0.001f));
  float sx = 0.f, sy = 0.f;
#pragma unroll
  for (int k2 = 0; k2 < 8; k2++) {
    float dm = powf(1000.0f, -(float)k2 / 8.0f);
    float a = 100.0f * dx * dm;
    float sn = sinf(a), cs = cosf(a);
    sx += sn * wg_w[h * 64 + k2]     + cs * wg_w[h * 64 + 32 + k2];
    sy += sn * wg_w[h * 64 + 8 + k2] + cs * wg_w[h * 64 + 40 + k2];
  }
  sxsyc[t] = sx;
  sxsyc[384 + t] = sy;
  if (dd == 0) {
    float c = wg_b[h];
#pragma unroll
    for (int k2 = 48; k2 < 64; k2++) c += wg_w[h * 64 + k2];
    sxsyc[768 + h] = c;
  }
}

// ---------------------------------------------------------------- V transpose to global Vt
__global__ __launch_bounds__(256) void vtrans_k(const u16* __restrict__ qkv_s,
                                                u16* __restrict__ Vt) {
  __shared__ u16 tile[64][33];
  int bh = blockIdx.y;
  int bt = bh / 12, h = bh % 12;
  int j0 = blockIdx.x * 32;            // 0..1120
  int tid = threadIdx.x;
#pragma unroll
  for (int it = 0; it < 8; it++) {
    int jj = it * 4 + (tid >> 6);
    int d = tid & 63;
    int j = j0 + jj;
    u16 v = 0;
    if (j < NSP) v = qkv_s[((long)bt * NSP + j) * 2304 + 1536 + h * 64 + d];
    tile[d][jj] = v;
  }
  __syncthreads();
#pragma unroll
  for (int it = 0; it < 8; it++) {
    int d = it * 8 + (tid >> 5);
    int j = tid & 31;
    Vt[((long)bh * 64 + d) * VT_LD + j0 + j] = tile[d][j];
  }
}

// ---------------------------------------------------------------- fused spatial attention (flash-style)
// grid (9 q-tiles, 96 bt*head), 256 threads. O = softmax(QK^T*0.125 + bias(geom)) V
__global__ __launch_bounds__(256) void attn_s_k(const u16* __restrict__ qkv,
                                                const u16* __restrict__ Vt,
                                                const float* __restrict__ sxsyc,
                                                u16* __restrict__ attn_o) {
  __shared__ u16 Ps[128][PS_LD];       // Q staging, then P tiles (per-wave rows)
  __shared__ u16 Ks[128][72];
  __shared__ float Bh[32][32];
  const int qt = blockIdx.x, bh = blockIdx.y;
  const int bt = bh / 12, h = bh % 12;
  const int tid = threadIdx.x;
  const int wave = tid >> 6, lane = tid & 63;
  const int quad = lane >> 4, lr = lane & 15;
  const int m0 = qt * 128;
  const long qb = (long)bt * NSP * 2304 + h * 64;

  // per-head bias table: Bh[dr][dc] = log(max(relu(sx+sy+c), 1e-6))
  for (int idx = tid; idx < 1024; idx += 256) {
    int dr = idx >> 5, dc = idx & 31;
    float v = sxsyc[h * 32 + dr] + sxsyc[384 + h * 32 + dc] + sxsyc[768 + h];
    Bh[dr][dc] = logf(fmaxf(fmaxf(v, 0.0f), 1e-6f));
  }
  // stage Q tile into Ps (cols 0..63)
#pragma unroll
  for (int s = 0; s < 4; s++) {
    int seg = tid + s * 256;
    int row = seg >> 3, c8 = (seg & 7) << 3;
    short8 v = (short8){0,0,0,0,0,0,0,0};
    int tok = m0 + row;
    if (tok < NSP) v = *(const short8*)(qkv + qb + (long)tok * 2304 + c8);
    *(short8*)&Ps[row][c8] = v;
  }
  __syncthreads();
  short8 qf[2][2];
#pragma unroll
  for (int i = 0; i < 2; i++)
#pragma unroll
    for (int ks = 0; ks < 2; ks++)
      qf[i][ks] = *(const short8*)&Ps[wave * 32 + i * 16 + lr][ks * 32 + quad * 8];

  f32x4 Oa[2][4];
  float mr[2][4], lsum[2][4];
#pragma unroll
  for (int i = 0; i < 2; i++)
#pragma unroll
    for (int n = 0; n < 4; n++) Oa[i][n] = (f32x4){0.f, 0.f, 0.f, 0.f};
#pragma unroll
  for (int i = 0; i < 2; i++)
#pragma unroll
    for (int r = 0; r < 4; r++) { mr[i][r] = -1e30f; lsum[i][r] = 0.f; }

  int rid[2][4], ri_[2][4], ci_[2][4];
  float rok[2][4];
#pragma unroll
  for (int i = 0; i < 2; i++)
#pragma unroll
    for (int r = 0; r < 4; r++) {
      int i0 = m0 + wave * 32 + i * 16 + quad * 4 + r;
      rid[i][r] = i0;
      int ii = i0 < NSP ? i0 : (NSP - 1);
      int im1 = ii > 0 ? ii - 1 : 0;
      ri_[i][r] = im1 >> 5;
      ci_[i][r] = im1 & 31;
      rok[i][r] = (i0 > 0) ? 1.0f : 0.0f;
    }

  for (int kt = 0; kt < 9; kt++) {
    __syncthreads();
    // stage K tile
#pragma unroll
    for (int s = 0; s < 4; s++) {
      int seg = tid + s * 256;
      int row = seg >> 3, c8 = (seg & 7) << 3;
      short8 v = (short8){0,0,0,0,0,0,0,0};
      int tok = kt * 128 + row;
      if (tok < NSP) v = *(const short8*)(qkv + qb + 768 + (long)tok * 2304 + c8);
      *(short8*)&Ks[row][c8] = v;
    }
    __syncthreads();
    // S = Q K^T
    f32x4 sa[2][8];
#pragma unroll
    for (int i = 0; i < 2; i++)
#pragma unroll
      for (int j = 0; j < 8; j++) sa[i][j] = (f32x4){0.f, 0.f, 0.f, 0.f};
#pragma unroll
    for (int ks = 0; ks < 2; ks++) {
      short8 kf[8];
#pragma unroll
      for (int j = 0; j < 8; j++)
        kf[j] = *(const short8*)&Ks[j * 16 + lr][ks * 32 + quad * 8];
#pragma unroll
      for (int i = 0; i < 2; i++)
#pragma unroll
        for (int j = 0; j < 8; j++)
          sa[i][j] = __builtin_amdgcn_mfma_f32_16x16x32_bf16(qf[i][ks], kf[j], sa[i][j], 0, 0, 0);
    }
    // scale + bias + column mask
#pragma unroll
    for (int j = 0; j < 8; j++) {
      int j0 = kt * 128 + j * 16 + lr;
      bool jv = j0 < NSP;
      int jm1 = j0 > 0 ? j0 - 1 : 0;
      int rj = jm1 >> 5; if (rj > 31) rj = 31;
      int cj = jm1 & 31;
      float jnz = (j0 > 0) ? 1.0f : 0.0f;
#pragma unroll
      for (int i = 0; i < 2; i++)
#pragma unroll
        for (int r = 0; r < 4; r++) {
          int ad = ri_[i][r] - rj; ad = ad < 0 ? -ad : ad;
          int cd = ci_[i][r] - cj; cd = cd < 0 ? -cd : cd;
          float sv = sa[i][j][r] * 0.125f + Bh[ad][cd] * jnz * rok[i][r];
          sa[i][j][r] = jv ? sv : -1e30f;
        }
    }
    // online softmax (rows distributed over 16-lane groups)
    float alpha[2][4];
#pragma unroll
    for (int i = 0; i < 2; i++)
#pragma unroll
      for (int r = 0; r < 4; r++) {
        float tm = sa[i][0][r];
#pragma unroll
        for (int j = 1; j < 8; j++) tm = fmaxf(tm, sa[i][j][r]);
        tm = fmaxf(tm, __shfl_xor(tm, 1));
        tm = fmaxf(tm, __shfl_xor(tm, 2));
        tm = fmaxf(tm, __shfl_xor(tm, 4));
        tm = fmaxf(tm, __shfl_xor(tm, 8));
        float mn = fmaxf(mr[i][r], tm);
        float a = __expf(mr[i][r] - mn);
        alpha[i][r] = a;
        float ls = 0.f;
#pragma unroll
        for (int j = 0; j < 8; j++) {
          float pp = __expf(sa[i][j][r] - mn);
          ls += pp;
          Ps[wave * 32 + i * 16 + quad * 4 + r][j * 16 + lr] = f2bf(pp);
        }
        lsum[i][r] = lsum[i][r] * a + ls;
        mr[i][r] = mn;
      }
    // O = O*alpha + P V
#pragma unroll
    for (int i = 0; i < 2; i++)
#pragma unroll
      for (int n = 0; n < 4; n++)
#pragma unroll
        for (int r = 0; r < 4; r++) Oa[i][n][r] *= alpha[i][r];
#pragma unroll
    for (int ks = 0; ks < 4; ks++) {
      short8 pf[2], vf[4];
#pragma unroll
      for (int i = 0; i < 2; i++)
        pf[i] = *(const short8*)&Ps[wave * 32 + i * 16 + lr][ks * 32 + quad * 8];
#pragma unroll
      for (int n = 0; n < 4; n++)
        vf[n] = *(const short8*)(Vt + ((long)bh * 64 + n * 16 + lr) * VT_LD + kt * 128 + ks * 32 + quad * 8);
#pragma unroll
      for (int i = 0; i < 2; i++)
#pragma unroll
        for (int n = 0; n < 4; n++)
          Oa[i][n] = __builtin_amdgcn_mfma_f32_16x16x32_bf16(pf[i], vf[n], Oa[i][n], 0, 0, 0);
    }
  }
  // finalize: reduce l across 16-lane group, normalize, store
#pragma unroll
  for (int i = 0; i < 2; i++)
#pragma unroll
    for (int r = 0; r < 4; r++) {
      float l = lsum[i][r];
      l += __shfl_xor(l, 1);
      l += __shfl_xor(l, 2);
      l += __shfl_xor(l, 4);
      l += __shfl_xor(l, 8);
      lsum[i][r] = 1.0f / l;
    }
#pragma unroll
  for (int i = 0; i < 2; i++)
#pragma unroll
    for (int r = 0; r < 4; r++) {
      int i0 = rid[i][r];
      if (i0 < NSP) {
        long ob = ((long)bt * NSP + i0) * 768 + h * 64;
#pragma unroll
        for (int n = 0; n < 4; n++)
          attn_o[ob + n * 16 + lr] = f2bf(Oa[i][n][r] * lsum[i][r]);
      }
    }
}

// ---------------------------------------------------------------- assemble xout_pre
__global__ __launch_bounds__(256) void assemble_k(const float* __restrict__ x,
                                                  const float* __restrict__ xt,
                                                  const float* __restrict__ res_s,
                                                  float* __restrict__ outp) {
  int n = blockIdx.x, bb = blockIdx.y;
  int tid = threadIdx.x;
  long ob = ((long)bb * 4097 + n) * DIM;
  if (n == 0) {
#pragma unroll
    for (int i = 0; i < 3; i++) {
      int c = tid + i * 256;
      float acc = x[ob + c];
#pragma unroll
      for (int t = 0; t < 4; t++)
        acc += 0.25f * res_s[((long)(bb * 4 + t) * NSP) * DIM + c];
      outp[ob + c] = acc;
    }
  } else {
    int q = n - 1, hw = q >> 2, t = q & 3;
    long rs = ((long)(bb * 4 + t) * NSP + 1 + hw) * DIM;
    long xb = ((long)bb * 4096 + q) * DIM;
#pragma unroll
    for (int i = 0; i < 3; i++) {
      int c = tid + i * 256;
      outp[ob + c] = xt[xb + c] + res_s[rs + c];
    }
  }
}

// ================================================================ host
extern "C" void kernel_launch(void* const* d_in, const int* in_sizes, int n_in,
                              void* d_out, int out_size, void* d_ws, size_t ws_size,
                              hipStream_t stream) {
  const float* x        = (const float*)d_in[0];
  const float* norm1_g  = (const float*)d_in[1];
  const float* norm1_b  = (const float*)d_in[2];
  const float* qkv_w    = (const float*)d_in[3];
  const float* proj_w   = (const float*)d_in[4];
  const float* proj_b   = (const float*)d_in[5];
  const float* wg_w     = (const float*)d_in[6];
  const float* wg_b     = (const float*)d_in[7];
  const float* tnorm1_g = (const float*)d_in[8];
  const float* tnorm1_b = (const float*)d_in[9];
  const float* tqkv_w   = (const float*)d_in[10];
  const float* tproj_w  = (const float*)d_in[11];
  const float* tproj_b  = (const float*)d_in[12];
  const float* tfc_w    = (const float*)d_in[13];
  const float* tfc_b    = (const float*)d_in[14];
  const float* norm2_g  = (const float*)d_in[15];
  const float* norm2_b  = (const float*)d_in[16];
  const float* fc1_w    = (const float*)d_in[17];
  const float* fc1_b    = (const float*)d_in[18];
  const float* fc2_w    = (const float*)d_in[19];
  const float* fc2_b    = (const float*)d_in[20];
  float* out = (float*)d_out;
  (void)in_sizes; (void)n_in; (void)out_size;

  char* base = (char*)d_ws;
  size_t off = 0;
  auto take = [&](size_t bytes) -> char* {
    char* p = base + off;
    off += (bytes + 255) & ~(size_t)255;
    return p;
  };

  // persistent
  u16* wb_tqkv = (u16*)take(2304LL * 768 * 2);
  u16* wb_tprj = (u16*)take(768LL * 768 * 2);
  u16* wb_tfc  = (u16*)take(768LL * 768 * 2);
  u16* wb_qkv  = (u16*)take(2304LL * 768 * 2);
  u16* wb_proj = (u16*)take(768LL * 768 * 2);
  u16* wb_fc1  = (u16*)take(3072LL * 768 * 2);
  u16* wb_fc2  = (u16*)take(3072LL * 768 * 2);
  float* xt_f  = (float*)take(8192LL * 768 * 4);
  float* sxsyc = (float*)take(4096);
  char* pool   = take(64536576);
  size_t REQ = off;

  // phase T (temporal)
  u16* qkv_t  = (u16*)(pool);                  // 37,748,736
  u16* ln_xt  = (u16*)(pool + 37748736);       // 12,582,912
  u16* attn_t = ln_xt;                         // reuse after qkv GEMM
  u16* h1     = (u16*)(pool + 50331648);       // 12,582,912
  // phase S (spatial)
  u16* qkv_s  = (u16*)(pool);                  // 37,785,600
  u16* ln_xs  = (u16*)(pool + 37785600);       // 12,595,200
  u16* attn_sp = ln_xs;                        // reuse after qkv GEMM
  u16* Vt     = (u16*)(pool + 50380800);       // 14,155,776
  float* res_s = (float*)(pool);               // 25,190,400 over dead qkv_s
  // phase M (MLP)
  u16* ln2b   = (u16*)(pool);                  // 12,585,984
  u16* geluh  = (u16*)(pool + 12585984);       // 50,343,936

  if (ws_size < REQ) {   // diagnosable fallback: absmax == max|ref| without crashing
    long n = 2LL * 4097 * 768;
    zero_k<<<dim3((n + 255) / 256), 256, 0, stream>>>(out, n);
    return;
  }

  // ---- weights -> bf16
  {
    struct { const float* s; u16* d; long n; } cv[7] = {
      {tqkv_w, wb_tqkv, 2304LL * 768}, {tproj_w, wb_tprj, 768LL * 768},
      {tfc_w, wb_tfc, 768LL * 768},    {qkv_w, wb_qkv, 2304LL * 768},
      {proj_w, wb_proj, 768LL * 768},  {fc1_w, wb_fc1, 3072LL * 768},
      {fc2_w, wb_fc2, 3072LL * 768}};
    for (int i = 0; i < 7; i++)
      cvt_k<<<dim3((cv[i].n + 255) / 256), 256, 0, stream>>>(cv[i].s, cv[i].d, cv[i].n);
  }
  geo_pre_k<<<1, 384, 0, stream>>>(wg_w, wg_b, sxsyc);

  // ---- temporal branch
  ln_xt_k<<<dim3(4096, 2), 256, 0, stream>>>(x, tnorm1_g, tnorm1_b, ln_xt);
  {
    GemmParams p{};
    p.A = ln_xt; p.lda = 768; p.B = wb_tqkv; p.ldb = 768;
    p.C = qkv_t; p.ldc = 2304; p.scale = 1.0f;
    p.M = 8192; p.N = 2304; p.K = 768;
    gemm_k<true, false, false, false><<<dim3(18, 64, 1), 256, 0, stream>>>(p);
  }
  attn_t_k<<<dim3(12, 2048), 64, 0, stream>>>(qkv_t, attn_t);
  {
    GemmParams p{};
    p.A = attn_t; p.lda = 768; p.B = wb_tprj; p.ldb = 768;
    p.C = h1; p.ldc = 768; p.bias = tproj_b; p.scale = 1.0f;
    p.M = 8192; p.N = 768; p.K = 768;
    gemm_k<true, true, false, false><<<dim3(6, 64, 1), 256, 0, stream>>>(p);
  }
  {
    GemmParams p{};
    p.A = h1; p.lda = 768; p.sA1 = 4096LL * 768;
    p.B = wb_tfc; p.ldb = 768;
    p.C = xt_f; p.ldc = 768; p.sC1 = 4096LL * 768;
    p.bias = tfc_b;
    p.resid = x + 768; p.ldr = 768; p.sR1 = 4097LL * 768;
    p.scale = 1.0f;
    p.M = 4096; p.N = 768; p.K = 768;
    gemm_k<false, true, true, false><<<dim3(6, 32, 2), 256, 0, stream>>>(p);
  }

  // ---- spatial branch
  ln_xs_k<<<dim3(NSP, 8), 256, 0, stream>>>(x, xt_f, norm1_g, norm1_b, ln_xs);
  {
    GemmParams p{};
    p.A = ln_xs; p.lda = 768; p.B = wb_qkv; p.ldb = 768;
    p.C = qkv_s; p.ldc = 2304; p.scale = 1.0f;
    p.M = 8200; p.N = 2304; p.K = 768;
    gemm_k<true, false, false, false><<<dim3(18, 65, 1), 256, 0, stream>>>(p);
  }
  vtrans_k<<<dim3(36, 96), 256, 0, stream>>>(qkv_s, Vt);
  attn_s_k<<<dim3(9, 96), 256, 0, stream>>>(qkv_s, Vt, sxsyc, attn_sp);
  {
    GemmParams p{};
    p.A = attn_sp; p.lda = 768; p.B = wb_proj; p.ldb = 768;
    p.C = res_s; p.ldc = 768; p.bias = proj_b; p.scale = 1.0f;
    p.M = 8200; p.N = 768; p.K = 768;
    gemm_k<false, true, false, false><<<dim3(6, 65, 1), 256, 0, stream>>>(p);
  }
  assemble_k<<<dim3(4097, 2), 256, 0, stream>>>(x, xt_f, res_s, out);

  // ---- MLP
  ln2_k<<<dim3(4097, 2), 256, 0, stream>>>(out, norm2_g, norm2_b, ln2b);
  {
    GemmParams p{};
    p.A = ln2b; p.lda = 768; p.B = wb_fc1; p.ldb = 768;
    p.C = geluh; p.ldc = 3072; p.bias = fc1_b; p.scale = 1.0f;
    p.M = 8194; p.N = 3072; p.K = 768;
    gemm_k<true, true, false, true><<<dim3(24, 65, 1), 256, 0, stream>>>(p);
  }
  {
    GemmParams p{};
    p.A = geluh; p.lda = 3072; p.B = wb_fc2; p.ldb = 3072;
    p.C = out; p.ldc = 768; p.bias = fc2_b;
    p.resid = out; p.ldr = 768; p.scale = 1.0f;
    p.M = 8194; p.N = 768; p.K = 3072;
    gemm_k<false, true, true, false><<<dim3(6, 65, 1), 256, 0, stream>>>(p);
  }
}

// Round 3
// 817.998 us; speedup vs baseline: 1.3589x; 1.3589x over previous
//
#include <hip/hip_runtime.h>
#include <stdint.h>

#define DIM   768
#define HEADS 12
#define NSP   1025      // spatial seq len (1 + 32*32)
#define VT_LD 1152      // padded row length of transposed V (= 9*128)
#define PS_LD 136       // P LDS leading dim (u16): 272 B rows, 16B-aligned

typedef __attribute__((ext_vector_type(8))) short short8;
typedef __attribute__((ext_vector_type(4))) float f32x4;
typedef unsigned short u16;
typedef unsigned int   u32;

__device__ __forceinline__ u16 f2bf(float v) {
  u32 u = __builtin_bit_cast(u32, v);
  u += 0x7fffu + ((u >> 16) & 1u);   // RNE
  return (u16)(u >> 16);
}
__device__ __forceinline__ float bf2f(u16 h) {
  u32 u = ((u32)h) << 16;
  return __builtin_bit_cast(float, u);
}

// async global->LDS, 16B per lane. ldsbase is wave-uniform; HW dest = base + lane*16.
__device__ __forceinline__ void load_lds16(const u16* g, u16* lbase, int lane) {
#if __has_builtin(__builtin_amdgcn_global_load_lds)
  __builtin_amdgcn_global_load_lds((const __attribute__((address_space(1))) void*)g,
                                   (__attribute__((address_space(3))) void*)lbase, 16, 0, 0);
#else
  *(short8*)(lbase + lane * 8) = *(const short8*)g;
#endif
}

// ---------------------------------------------------------------- utility
__global__ __launch_bounds__(256) void zero_k(float* __restrict__ o, long n) {
  long i = (long)blockIdx.x * 256 + threadIdx.x;
  if (i < n) o[i] = 0.0f;
}

__global__ __launch_bounds__(256) void cvt_k(const float* __restrict__ src,
                                             u16* __restrict__ dst, long n) {
  long i = (long)blockIdx.x * 256 + threadIdx.x;
  if (i < n) dst[i] = f2bf(src[i]);
}

// ---------------------------------------------------------------- layernorm
__device__ __forceinline__ void ln_row(const float* __restrict__ src,
                                       u16* __restrict__ dst,
                                       const float* __restrict__ g,
                                       const float* __restrict__ b) {
  int tid = threadIdx.x;
  float v[3];
  float s = 0.f, ss = 0.f;
#pragma unroll
  for (int i = 0; i < 3; i++) {
    v[i] = src[tid + i * 256];
    s += v[i];
    ss += v[i] * v[i];
  }
  __shared__ float red[8];
#pragma unroll
  for (int m = 32; m; m >>= 1) {
    s  += __shfl_xor(s, m);
    ss += __shfl_xor(ss, m);
  }
  int wid = tid >> 6;
  if ((tid & 63) == 0) { red[wid] = s; red[4 + wid] = ss; }
  __syncthreads();
  s  = red[0] + red[1] + red[2] + red[3];
  ss = red[4] + red[5] + red[6] + red[7];
  float mean = s * (1.0f / 768.0f);
  float var  = ss * (1.0f / 768.0f) - mean * mean;
  float rs = rsqrtf(var + 1e-5f);
#pragma unroll
  for (int i = 0; i < 3; i++) {
    int c = tid + i * 256;
    dst[c] = f2bf((v[i] - mean) * rs * g[c] + b[c]);
  }
}

__global__ __launch_bounds__(256) void ln_xt_k(const float* __restrict__ x,
                                               const float* __restrict__ g,
                                               const float* __restrict__ b,
                                               u16* __restrict__ outb) {
  int q = blockIdx.x, bb = blockIdx.y;
  const float* src = x + ((long)bb * 4097 + 1 + q) * DIM;
  u16* dst = outb + ((long)bb * 4096 + q) * DIM;
  ln_row(src, dst, g, b);
}

__global__ __launch_bounds__(256) void ln_xs_k(const float* __restrict__ x,
                                               const float* __restrict__ xt,
                                               const float* __restrict__ g,
                                               const float* __restrict__ b,
                                               u16* __restrict__ outb) {
  int n = blockIdx.x, bt = blockIdx.y;
  int bb = bt >> 2, t = bt & 3;
  const float* src;
  if (n == 0) src = x + (long)bb * 4097 * DIM;
  else        src = xt + ((long)bb * 4096 + (long)(n - 1) * 4 + t) * DIM;
  u16* dst = outb + ((long)bt * NSP + n) * DIM;
  ln_row(src, dst, g, b);
}

__global__ __launch_bounds__(256) void ln2_k(const float* __restrict__ xo,
                                             const float* __restrict__ g,
                                             const float* __restrict__ b,
                                             u16* __restrict__ outb) {
  int n = blockIdx.x, bb = blockIdx.y;
  const float* src = xo + ((long)bb * 4097 + n) * DIM;
  u16* dst = outb + ((long)bb * 4097 + n) * DIM;
  ln_row(src, dst, g, b);
}

// ---------------------------------------------------------------- GEMM (m97-style staging)
// C[M,N] = act( scale*(A[M,K] @ W[N,K]^T) + bias ) + resid   (batched via z)
struct GemmParams {
  const u16* A; long lda, sA1;
  const u16* B; long ldb;
  void* C;      long ldc, sC1;
  const float* bias;
  const float* resid; long ldr, sR1;
  float scale;
  int M, N, K;
};

template <bool OUTBF16, bool BIASV, bool RESID, bool GELU_>
__global__ __launch_bounds__(256) void gemm_k(GemmParams p) {
  __shared__ u16 As[4096];   // 128 x 32, unpadded (global_load_lds needs lane-contiguous)
  __shared__ u16 Bs[4096];
  int tid = threadIdx.x;
  int z1 = blockIdx.z;
  const u16* A = p.A + (long)z1 * p.sA1;
  const u16* B = p.B;
  int m0 = blockIdx.y * 128, n0 = blockIdx.x * 128;
  int wave = tid >> 6, lane = tid & 63;
  int quad = lane >> 4, lrow = lane & 15;
  int wm = (wave & 1) * 64, wn = (wave >> 1) * 64;

  // staging coords: seg = tid + s*256; row = seg>>2, col8 = (seg&3)*8; clamp rows (tails masked in epilogue)
  int rA0 = m0 + (tid >> 2);        if (rA0 > p.M - 1) rA0 = p.M - 1;
  int rA1 = m0 + 64 + (tid >> 2);   if (rA1 > p.M - 1) rA1 = p.M - 1;
  int rB0 = n0 + (tid >> 2);        if (rB0 > p.N - 1) rB0 = p.N - 1;
  int rB1 = n0 + 64 + (tid >> 2);   if (rB1 > p.N - 1) rB1 = p.N - 1;
  int c8 = (tid & 3) << 3;
  const u16* pa0 = A + (long)rA0 * p.lda + c8;
  const u16* pa1 = A + (long)rA1 * p.lda + c8;
  const u16* pb0 = B + (long)rB0 * p.ldb + c8;
  const u16* pb1 = B + (long)rB1 * p.ldb + c8;
  u16* lA0 = As + wave * 512;  u16* lA1 = As + 2048 + wave * 512;
  u16* lB0 = Bs + wave * 512;  u16* lB1 = Bs + 2048 + wave * 512;

  f32x4 acc[4][4];
#pragma unroll
  for (int i = 0; i < 4; i++)
#pragma unroll
    for (int j = 0; j < 4; j++) acc[i][j] = (f32x4){0.f, 0.f, 0.f, 0.f};

  for (int k0 = 0; k0 < p.K; k0 += 32) {
    load_lds16(pa0 + k0, lA0, lane);
    load_lds16(pa1 + k0, lA1, lane);
    load_lds16(pb0 + k0, lB0, lane);
    load_lds16(pb1 + k0, lB1, lane);
    __syncthreads();
    short8 af[4], bfr[4];
#pragma unroll
    for (int i = 0; i < 4; i++) af[i]  = *(const short8*)&As[(wm + i * 16 + lrow) * 32 + quad * 8];
#pragma unroll
    for (int j = 0; j < 4; j++) bfr[j] = *(const short8*)&Bs[(wn + j * 16 + lrow) * 32 + quad * 8];
#pragma unroll
    for (int i = 0; i < 4; i++)
#pragma unroll
      for (int j = 0; j < 4; j++)
        acc[i][j] = __builtin_amdgcn_mfma_f32_16x16x32_bf16(af[i], bfr[j], acc[i][j], 0, 0, 0);
    __syncthreads();
  }

  float* Cf = (float*)p.C;
  u16*   Ch = (u16*)p.C;
  long cbase = (long)z1 * p.sC1;
#pragma unroll
  for (int i = 0; i < 4; i++) {
    int rbase = m0 + wm + i * 16 + quad * 4;
#pragma unroll
    for (int j = 0; j < 4; j++) {
      int c = n0 + wn + j * 16 + lrow;
      if (c >= p.N) continue;
#pragma unroll
      for (int rr = 0; rr < 4; rr++) {
        int r = rbase + rr;
        if (r >= p.M) continue;
        float v = acc[i][j][rr] * p.scale;
        if (BIASV) v += p.bias[c];
        if (GELU_) v = 0.5f * v * (1.0f + erff(v * 0.70710678118654752f));
        if (RESID) v += p.resid[(long)z1 * p.sR1 + (long)r * p.ldr + c];
        long o = cbase + (long)r * p.ldc + c;
        if (OUTBF16) Ch[o] = f2bf(v);
        else         Cf[o] = v;
      }
    }
  }
}

// ---------------------------------------------------------------- temporal attention (T=4)
__global__ __launch_bounds__(64) void attn_t_k(const u16* __restrict__ qkv,
                                               u16* __restrict__ outb) {
  int h = blockIdx.x;
  int g = blockIdx.y;
  int d = threadIdx.x;
  long base = (long)g * 4 * 2304 + h * 64 + d;
  float q[4], k[4], vv[4];
#pragma unroll
  for (int t = 0; t < 4; t++) {
    q[t]  = bf2f(qkv[base + (long)t * 2304]);
    k[t]  = bf2f(qkv[base + (long)t * 2304 + 768]);
    vv[t] = bf2f(qkv[base + (long)t * 2304 + 1536]);
  }
  float sc[4][4];
#pragma unroll
  for (int i = 0; i < 4; i++)
#pragma unroll
    for (int j = 0; j < 4; j++) {
      float pv = q[i] * k[j];
#pragma unroll
      for (int m = 32; m; m >>= 1) pv += __shfl_xor(pv, m);
      sc[i][j] = pv * 0.125f;
    }
#pragma unroll
  for (int i = 0; i < 4; i++) {
    float mx = fmaxf(fmaxf(sc[i][0], sc[i][1]), fmaxf(sc[i][2], sc[i][3]));
    float e0 = __expf(sc[i][0] - mx), e1 = __expf(sc[i][1] - mx);
    float e2 = __expf(sc[i][2] - mx), e3 = __expf(sc[i][3] - mx);
    float inv = 1.0f / (e0 + e1 + e2 + e3);
    float ov = (e0 * vv[0] + e1 * vv[1] + e2 * vv[2] + e3 * vv[3]) * inv;
    outb[((long)g * 4 + i) * DIM + h * 64 + d] = f2bf(ov);
  }
}

// ---------------------------------------------------------------- geometry tables
__global__ void geo_pre_k(const float* __restrict__ wg_w,
                          const float* __restrict__ wg_b,
                          float* __restrict__ sxsyc) {
  int t = threadIdx.x;
  if (t >= 384) return;
  int h = t >> 5, dd = t & 31;
  float dx = logf(fmaxf((float)dd * (1.0f / 33.0f), 0.001f));
  float sx = 0.f, sy = 0.f;
#pragma unroll
  for (int k2 = 0; k2 < 8; k2++) {
    float dm = powf(1000.0f, -(float)k2 / 8.0f);
    float a = 100.0f * dx * dm;
    float sn = sinf(a), cs = cosf(a);
    sx += sn * wg_w[h * 64 + k2]     + cs * wg_w[h * 64 + 32 + k2];
    sy += sn * wg_w[h * 64 + 8 + k2] + cs * wg_w[h * 64 + 40 + k2];
  }
  sxsyc[t] = sx;
  sxsyc[384 + t] = sy;
  if (dd == 0) {
    float c = wg_b[h];
#pragma unroll
    for (int k2 = 48; k2 < 64; k2++) c += wg_w[h * 64 + k2];
    sxsyc[768 + h] = c;
  }
}

// Bh_g[h][dr][dc] = log(max(relu(sx+sy+c), 1e-6))
__global__ __launch_bounds__(256) void geo_bias_k(const float* __restrict__ sxsyc,
                                                  float* __restrict__ Bh_g) {
  int h = blockIdx.x / 4;
  int idx = (blockIdx.x % 4) * 256 + threadIdx.x;   // 0..1023
  int dr = idx >> 5, dc = idx & 31;
  float v = sxsyc[h * 32 + dr] + sxsyc[384 + h * 32 + dc] + sxsyc[768 + h];
  Bh_g[h * 1024 + idx] = logf(fmaxf(fmaxf(v, 0.0f), 1e-6f));
}

// ---------------------------------------------------------------- V transpose to global Vt
__global__ __launch_bounds__(256) void vtrans_k(const u16* __restrict__ qkv_s,
                                                u16* __restrict__ Vt) {
  __shared__ u16 tile[64][33];
  int bh = blockIdx.y;
  int bt = bh / 12, h = bh % 12;
  int j0 = blockIdx.x * 32;
  int tid = threadIdx.x;
#pragma unroll
  for (int it = 0; it < 8; it++) {
    int jj = it * 4 + (tid >> 6);
    int d = tid & 63;
    int j = j0 + jj;
    u16 v = 0;
    if (j < NSP) v = qkv_s[((long)bt * NSP + j) * 2304 + 1536 + h * 64 + d];
    tile[d][jj] = v;
  }
  __syncthreads();
#pragma unroll
  for (int it = 0; it < 8; it++) {
    int d = it * 8 + (tid >> 5);
    int j = tid & 31;
    Vt[((long)bh * 64 + d) * VT_LD + j0 + j] = tile[d][j];
  }
}

// ---------------------------------------------------------------- fused spatial attention
// grid (17 q-tiles of 64 rows, 96 bt*head), 256 threads, one 16-row strip per wave.
__global__ __launch_bounds__(256, 4) void attn_s_k(const u16* __restrict__ qkv,
                                                   const u16* __restrict__ Vt,
                                                   const float* __restrict__ Bh_g,
                                                   u16* __restrict__ attn_o) {
  __shared__ u16 KsF[8192];     // 2 sub-tiles x (128 rows x 32 cols)
  __shared__ u16 UN[8704];      // union: Q staging (2 x 64 x 32) then P (64 x PS_LD)
  __shared__ float BhS[1024];
  const int qt = blockIdx.x, bh = blockIdx.y;
  const int bt = bh / 12, h = bh % 12;
  const int tid = threadIdx.x;
  const int wave = tid >> 6, lane = tid & 63;
  const int quad = lane >> 4, lr = lane & 15;
  const int m0 = qt * 64;
  const long qb = (long)bt * NSP * 2304 + h * 64;

  // bias table -> LDS
#pragma unroll
  for (int i = 0; i < 4; i++) BhS[tid + i * 256] = Bh_g[h * 1024 + tid + i * 256];

  // stage Q (64 x 64) as 2 sub-tiles of 64x32
  {
    int rowq = tid >> 2, colq = (tid & 3) << 3;
    int tokq = m0 + rowq; if (tokq > 1024) tokq = 1024;
    const u16* gq = qkv + qb + (long)tokq * 2304 + colq;
    load_lds16(gq,      UN + wave * 512, lane);
    load_lds16(gq + 32, UN + 2048 + wave * 512, lane);
  }
  __syncthreads();
  short8 qf[2];
#pragma unroll
  for (int ks = 0; ks < 2; ks++)
    qf[ks] = *(const short8*)&UN[ks * 2048 + (wave * 16 + lr) * 32 + quad * 8];

  f32x4 Oa[4];
  float mr[4], lsum[4];
#pragma unroll
  for (int n = 0; n < 4; n++) Oa[n] = (f32x4){0.f, 0.f, 0.f, 0.f};
#pragma unroll
  for (int r = 0; r < 4; r++) { mr[r] = -1e30f; lsum[r] = 0.f; }

  int rid[4], ri_[4], ci_[4];
  float rok[4];
#pragma unroll
  for (int r = 0; r < 4; r++) {
    int i0 = m0 + wave * 16 + quad * 4 + r;
    rid[r] = i0;
    int ii = i0 < NSP ? i0 : (NSP - 1);
    int im1 = ii > 0 ? ii - 1 : 0;
    ri_[r] = im1 >> 5;
    ci_[r] = im1 & 31;
    rok[r] = (i0 > 0) ? 1.0f : 0.0f;
  }

  // K staging coords
  int rowk = tid >> 2, colk = (tid & 3) << 3;

  for (int kt = 0; kt < 9; kt++) {
    __syncthreads();    // prev iter's kf reads + (kt=0) qf reads drained
    {
      int t0 = kt * 128 + rowk;      if (t0 > 1024) t0 = 1024;
      int t1 = kt * 128 + 64 + rowk; if (t1 > 1024) t1 = 1024;
      const u16* g0 = qkv + qb + 768 + (long)t0 * 2304 + colk;
      const u16* g1 = qkv + qb + 768 + (long)t1 * 2304 + colk;
      load_lds16(g0,      KsF + wave * 512, lane);
      load_lds16(g1,      KsF + 2048 + wave * 512, lane);
      load_lds16(g0 + 32, KsF + 4096 + wave * 512, lane);
      load_lds16(g1 + 32, KsF + 6144 + wave * 512, lane);
    }
    __syncthreads();
    // S strip = Q(16) K^T(128)
    f32x4 sa[8];
#pragma unroll
    for (int j = 0; j < 8; j++) sa[j] = (f32x4){0.f, 0.f, 0.f, 0.f};
#pragma unroll
    for (int ks = 0; ks < 2; ks++) {
#pragma unroll
      for (int j = 0; j < 8; j++) {
        short8 kf = *(const short8*)&KsF[ks * 4096 + (j * 16 + lr) * 32 + quad * 8];
        sa[j] = __builtin_amdgcn_mfma_f32_16x16x32_bf16(qf[ks], kf, sa[j], 0, 0, 0);
      }
    }
    // scale + geometric bias + column mask
#pragma unroll
    for (int j = 0; j < 8; j++) {
      int j0 = kt * 128 + j * 16 + lr;
      bool jv = j0 < NSP;
      int jm1 = j0 > 0 ? j0 - 1 : 0;
      if (jm1 > 1023) jm1 = 1023;
      int rj = jm1 >> 5, cj = jm1 & 31;
      float jnz = (j0 > 0) ? 1.0f : 0.0f;
#pragma unroll
      for (int r = 0; r < 4; r++) {
        int ad = ri_[r] - rj; ad = ad < 0 ? -ad : ad;
        int cd = ci_[r] - cj; cd = cd < 0 ? -cd : cd;
        float sv = sa[j][r] * 0.125f + BhS[ad * 32 + cd] * jnz * rok[r];
        sa[j][r] = jv ? sv : -1e30f;
      }
    }
    // online softmax; P -> LDS (union region, own wave's rows only)
    float alpha[4];
#pragma unroll
    for (int r = 0; r < 4; r++) {
      float tm = sa[0][r];
#pragma unroll
      for (int j = 1; j < 8; j++) tm = fmaxf(tm, sa[j][r]);
      tm = fmaxf(tm, __shfl_xor(tm, 1));
      tm = fmaxf(tm, __shfl_xor(tm, 2));
      tm = fmaxf(tm, __shfl_xor(tm, 4));
      tm = fmaxf(tm, __shfl_xor(tm, 8));
      float mn = fmaxf(mr[r], tm);
      float a = __expf(mr[r] - mn);
      alpha[r] = a;
      float ls = 0.f;
      int prow = (wave * 16 + quad * 4 + r) * PS_LD;
#pragma unroll
      for (int j = 0; j < 8; j++) {
        float pp = __expf(sa[j][r] - mn);
        ls += pp;
        UN[prow + j * 16 + lr] = f2bf(pp);
      }
      lsum[r] = lsum[r] * a + ls;
      mr[r] = mn;
    }
#pragma unroll
    for (int n = 0; n < 4; n++)
#pragma unroll
      for (int r = 0; r < 4; r++) Oa[n][r] *= alpha[r];
    // O += P V  (P from LDS, V fragments straight from global Vt)
#pragma unroll
    for (int ks = 0; ks < 4; ks++) {
      short8 pf = *(const short8*)&UN[(wave * 16 + lr) * PS_LD + ks * 32 + quad * 8];
#pragma unroll
      for (int n = 0; n < 4; n++) {
        short8 vf = *(const short8*)(Vt + ((long)bh * 64 + n * 16 + lr) * VT_LD + kt * 128 + ks * 32 + quad * 8);
        Oa[n] = __builtin_amdgcn_mfma_f32_16x16x32_bf16(pf, vf, Oa[n], 0, 0, 0);
      }
    }
  }
  // finalize
#pragma unroll
  for (int r = 0; r < 4; r++) {
    float l = lsum[r];
    l += __shfl_xor(l, 1);
    l += __shfl_xor(l, 2);
    l += __shfl_xor(l, 4);
    l += __shfl_xor(l, 8);
    lsum[r] = 1.0f / l;
  }
#pragma unroll
  for (int r = 0; r < 4; r++) {
    int i0 = rid[r];
    if (i0 < NSP) {
      long ob = ((long)bt * NSP + i0) * 768 + h * 64;
#pragma unroll
      for (int n = 0; n < 4; n++)
        attn_o[ob + n * 16 + lr] = f2bf(Oa[n][r] * lsum[r]);
    }
  }
}

// ---------------------------------------------------------------- assemble xout_pre
__global__ __launch_bounds__(256) void assemble_k(const float* __restrict__ x,
                                                  const float* __restrict__ xt,
                                                  const float* __restrict__ res_s,
                                                  float* __restrict__ outp) {
  int n = blockIdx.x, bb = blockIdx.y;
  int tid = threadIdx.x;
  long ob = ((long)bb * 4097 + n) * DIM;
  if (n == 0) {
#pragma unroll
    for (int i = 0; i < 3; i++) {
      int c = tid + i * 256;
      float acc = x[ob + c];
#pragma unroll
      for (int t = 0; t < 4; t++)
        acc += 0.25f * res_s[((long)(bb * 4 + t) * NSP) * DIM + c];
      outp[ob + c] = acc;
    }
  } else {
    int q = n - 1, hw = q >> 2, t = q & 3;
    long rs = ((long)(bb * 4 + t) * NSP + 1 + hw) * DIM;
    long xb = ((long)bb * 4096 + q) * DIM;
#pragma unroll
    for (int i = 0; i < 3; i++) {
      int c = tid + i * 256;
      outp[ob + c] = xt[xb + c] + res_s[rs + c];
    }
  }
}

// ================================================================ host
extern "C" void kernel_launch(void* const* d_in, const int* in_sizes, int n_in,
                              void* d_out, int out_size, void* d_ws, size_t ws_size,
                              hipStream_t stream) {
  const float* x        = (const float*)d_in[0];
  const float* norm1_g  = (const float*)d_in[1];
  const float* norm1_b  = (const float*)d_in[2];
  const float* qkv_w    = (const float*)d_in[3];
  const float* proj_w   = (const float*)d_in[4];
  const float* proj_b   = (const float*)d_in[5];
  const float* wg_w     = (const float*)d_in[6];
  const float* wg_b     = (const float*)d_in[7];
  const float* tnorm1_g = (const float*)d_in[8];
  const float* tnorm1_b = (const float*)d_in[9];
  const float* tqkv_w   = (const float*)d_in[10];
  const float* tproj_w  = (const float*)d_in[11];
  const float* tproj_b  = (const float*)d_in[12];
  const float* tfc_w    = (const float*)d_in[13];
  const float* tfc_b    = (const float*)d_in[14];
  const float* norm2_g  = (const float*)d_in[15];
  const float* norm2_b  = (const float*)d_in[16];
  const float* fc1_w    = (const float*)d_in[17];
  const float* fc1_b    = (const float*)d_in[18];
  const float* fc2_w    = (const float*)d_in[19];
  const float* fc2_b    = (const float*)d_in[20];
  float* out = (float*)d_out;
  (void)in_sizes; (void)n_in; (void)out_size;

  char* base = (char*)d_ws;
  size_t off = 0;
  auto take = [&](size_t bytes) -> char* {
    char* p = base + off;
    off += (bytes + 255) & ~(size_t)255;
    return p;
  };

  // persistent
  u16* wb_tqkv = (u16*)take(2304LL * 768 * 2);
  u16* wb_tprj = (u16*)take(768LL * 768 * 2);
  u16* wb_tfc  = (u16*)take(768LL * 768 * 2);
  u16* wb_qkv  = (u16*)take(2304LL * 768 * 2);
  u16* wb_proj = (u16*)take(768LL * 768 * 2);
  u16* wb_fc1  = (u16*)take(3072LL * 768 * 2);
  u16* wb_fc2  = (u16*)take(3072LL * 768 * 2);
  float* xt_f  = (float*)take(8192LL * 768 * 4);
  float* sxsyc = (float*)take(4096);
  float* Bh_g  = (float*)take(12LL * 1024 * 4);
  char* pool   = take(64536576);
  size_t REQ = off;

  // phase T (temporal)
  u16* qkv_t  = (u16*)(pool);                  // 37,748,736
  u16* ln_xt  = (u16*)(pool + 37748736);       // 12,582,912
  u16* attn_t = ln_xt;
  u16* h1     = (u16*)(pool + 50331648);       // 12,582,912
  // phase S (spatial)
  u16* qkv_s  = (u16*)(pool);                  // 37,785,600
  u16* ln_xs  = (u16*)(pool + 37785600);       // 12,595,200
  u16* attn_sp = ln_xs;
  u16* Vt     = (u16*)(pool + 50380800);       // 14,155,776
  float* res_s = (float*)(pool);               // 25,190,400 over dead qkv_s
  // phase M (MLP)
  u16* ln2b   = (u16*)(pool);                  // 12,585,984
  u16* geluh  = (u16*)(pool + 12585984);       // 50,343,936

  if (ws_size < REQ) {   // diagnosable fallback
    long n = 2LL * 4097 * 768;
    zero_k<<<dim3((n + 255) / 256), 256, 0, stream>>>(out, n);
    return;
  }

  // ---- weights -> bf16
  {
    struct { const float* s; u16* d; long n; } cv[7] = {
      {tqkv_w, wb_tqkv, 2304LL * 768}, {tproj_w, wb_tprj, 768LL * 768},
      {tfc_w, wb_tfc, 768LL * 768},    {qkv_w, wb_qkv, 2304LL * 768},
      {proj_w, wb_proj, 768LL * 768},  {fc1_w, wb_fc1, 3072LL * 768},
      {fc2_w, wb_fc2, 3072LL * 768}};
    for (int i = 0; i < 7; i++)
      cvt_k<<<dim3((cv[i].n + 255) / 256), 256, 0, stream>>>(cv[i].s, cv[i].d, cv[i].n);
  }
  geo_pre_k<<<1, 384, 0, stream>>>(wg_w, wg_b, sxsyc);
  geo_bias_k<<<48, 256, 0, stream>>>(sxsyc, Bh_g);

  // ---- temporal branch
  ln_xt_k<<<dim3(4096, 2), 256, 0, stream>>>(x, tnorm1_g, tnorm1_b, ln_xt);
  {
    GemmParams p{};
    p.A = ln_xt; p.lda = 768; p.B = wb_tqkv; p.ldb = 768;
    p.C = qkv_t; p.ldc = 2304; p.scale = 1.0f;
    p.M = 8192; p.N = 2304; p.K = 768;
    gemm_k<true, false, false, false><<<dim3(18, 64, 1), 256, 0, stream>>>(p);
  }
  attn_t_k<<<dim3(12, 2048), 64, 0, stream>>>(qkv_t, attn_t);
  {
    GemmParams p{};
    p.A = attn_t; p.lda = 768; p.B = wb_tprj; p.ldb = 768;
    p.C = h1; p.ldc = 768; p.bias = tproj_b; p.scale = 1.0f;
    p.M = 8192; p.N = 768; p.K = 768;
    gemm_k<true, true, false, false><<<dim3(6, 64, 1), 256, 0, stream>>>(p);
  }
  {
    GemmParams p{};
    p.A = h1; p.lda = 768; p.sA1 = 4096LL * 768;
    p.B = wb_tfc; p.ldb = 768;
    p.C = xt_f; p.ldc = 768; p.sC1 = 4096LL * 768;
    p.bias = tfc_b;
    p.resid = x + 768; p.ldr = 768; p.sR1 = 4097LL * 768;
    p.scale = 1.0f;
    p.M = 4096; p.N = 768; p.K = 768;
    gemm_k<false, true, true, false><<<dim3(6, 32, 2), 256, 0, stream>>>(p);
  }

  // ---- spatial branch
  ln_xs_k<<<dim3(NSP, 8), 256, 0, stream>>>(x, xt_f, norm1_g, norm1_b, ln_xs);
  {
    GemmParams p{};
    p.A = ln_xs; p.lda = 768; p.B = wb_qkv; p.ldb = 768;
    p.C = qkv_s; p.ldc = 2304; p.scale = 1.0f;
    p.M = 8200; p.N = 2304; p.K = 768;
    gemm_k<true, false, false, false><<<dim3(18, 65, 1), 256, 0, stream>>>(p);
  }
  vtrans_k<<<dim3(36, 96), 256, 0, stream>>>(qkv_s, Vt);
  attn_s_k<<<dim3(17, 96), 256, 0, stream>>>(qkv_s, Vt, Bh_g, attn_sp);
  {
    GemmParams p{};
    p.A = attn_sp; p.lda = 768; p.B = wb_proj; p.ldb = 768;
    p.C = res_s; p.ldc = 768; p.bias = proj_b; p.scale = 1.0f;
    p.M = 8200; p.N = 768; p.K = 768;
    gemm_k<false, true, false, false><<<dim3(6, 65, 1), 256, 0, stream>>>(p);
  }
  assemble_k<<<dim3(4097, 2), 256, 0, stream>>>(x, xt_f, res_s, out);

  // ---- MLP
  ln2_k<<<dim3(4097, 2), 256, 0, stream>>>(out, norm2_g, norm2_b, ln2b);
  {
    GemmParams p{};
    p.A = ln2b; p.lda = 768; p.B = wb_fc1; p.ldb = 768;
    p.C = geluh; p.ldc = 3072; p.bias = fc1_b; p.scale = 1.0f;
    p.M = 8194; p.N = 3072; p.K = 768;
    gemm_k<true, true, false, true><<<dim3(24, 65, 1), 256, 0, stream>>>(p);
  }
  {
    GemmParams p{};
    p.A = geluh; p.lda = 3072; p.B = wb_fc2; p.ldb = 3072;
    p.C = out; p.ldc = 768; p.bias = fc2_b;
    p.resid = out; p.ldr = 768; p.scale = 1.0f;
    p.M = 8194; p.N = 768; p.K = 3072;
    gemm_k<false, true, true, false><<<dim3(6, 65, 1), 256, 0, stream>>>(p);
  }
}

// Round 5
// 744.937 us; speedup vs baseline: 1.4922x; 1.0981x over previous
//
#include <hip/hip_runtime.h>
#include <stdint.h>

#define DIM   768
#define HEADS 12
#define NSP   1025      // spatial seq len (1 + 32*32)
#define VT_LD 1152      // padded row length of transposed V
#define PS_LD 72        // P LDS leading dim (u16)

typedef __attribute__((ext_vector_type(8))) short short8;
typedef __attribute__((ext_vector_type(4))) float f32x4;
typedef unsigned short u16;
typedef unsigned int   u32;

__device__ __forceinline__ u16 f2bf(float v) {
  u32 u = __builtin_bit_cast(u32, v);
  u += 0x7fffu + ((u >> 16) & 1u);   // RNE
  return (u16)(u >> 16);
}
__device__ __forceinline__ float bf2f(u16 h) {
  u32 u = ((u32)h) << 16;
  return __builtin_bit_cast(float, u);
}

// async global->LDS, 16B per lane. lbase is wave-uniform; HW dest = base + lane*16.
__device__ __forceinline__ void load_lds16(const u16* g, u16* lbase, int lane) {
#if __has_builtin(__builtin_amdgcn_global_load_lds)
  __builtin_amdgcn_global_load_lds((const __attribute__((address_space(1))) void*)g,
                                   (__attribute__((address_space(3))) void*)lbase, 16, 0, 0);
#else
  *(short8*)(lbase + lane * 8) = *(const short8*)g;
#endif
}

// ---------------------------------------------------------------- utility
__global__ __launch_bounds__(256) void zero_k(float* __restrict__ o, long n) {
  long i = (long)blockIdx.x * 256 + threadIdx.x;
  if (i < n) o[i] = 0.0f;
}

__global__ __launch_bounds__(256) void cvt_k(const float* __restrict__ src,
                                             u16* __restrict__ dst, long n) {
  long i = (long)blockIdx.x * 256 + threadIdx.x;
  if (i < n) dst[i] = f2bf(src[i]);
}

// ---------------------------------------------------------------- layernorm
__device__ __forceinline__ void ln_row(const float* __restrict__ src,
                                       u16* __restrict__ dst,
                                       const float* __restrict__ g,
                                       const float* __restrict__ b) {
  int tid = threadIdx.x;
  float v[3];
  float s = 0.f, ss = 0.f;
#pragma unroll
  for (int i = 0; i < 3; i++) {
    v[i] = src[tid + i * 256];
    s += v[i];
    ss += v[i] * v[i];
  }
  __shared__ float red[8];
#pragma unroll
  for (int m = 32; m; m >>= 1) {
    s  += __shfl_xor(s, m);
    ss += __shfl_xor(ss, m);
  }
  int wid = tid >> 6;
  if ((tid & 63) == 0) { red[wid] = s; red[4 + wid] = ss; }
  __syncthreads();
  s  = red[0] + red[1] + red[2] + red[3];
  ss = red[4] + red[5] + red[6] + red[7];
  float mean = s * (1.0f / 768.0f);
  float var  = ss * (1.0f / 768.0f) - mean * mean;
  float rs = rsqrtf(var + 1e-5f);
#pragma unroll
  for (int i = 0; i < 3; i++) {
    int c = tid + i * 256;
    dst[c] = f2bf((v[i] - mean) * rs * g[c] + b[c]);
  }
}

__global__ __launch_bounds__(256) void ln_xt_k(const float* __restrict__ x,
                                               const float* __restrict__ g,
                                               const float* __restrict__ b,
                                               u16* __restrict__ outb) {
  int q = blockIdx.x, bb = blockIdx.y;
  const float* src = x + ((long)bb * 4097 + 1 + q) * DIM;
  u16* dst = outb + ((long)bb * 4096 + q) * DIM;
  ln_row(src, dst, g, b);
}

__global__ __launch_bounds__(256) void ln_xs_k(const float* __restrict__ x,
                                               const float* __restrict__ xt,
                                               const float* __restrict__ g,
                                               const float* __restrict__ b,
                                               u16* __restrict__ outb) {
  int n = blockIdx.x, bt = blockIdx.y;
  int bb = bt >> 2, t = bt & 3;
  const float* src;
  if (n == 0) src = x + (long)bb * 4097 * DIM;
  else        src = xt + ((long)bb * 4096 + (long)(n - 1) * 4 + t) * DIM;
  u16* dst = outb + ((long)bt * NSP + n) * DIM;
  ln_row(src, dst, g, b);
}

// ---------------------------------------------------------------- GEMM
// C[M,N] = act( scale*(A[M,K] @ W[N,K]^T) + bias ) + resid   (batched via z)
// NT64: 128x64 block tile (for narrow-N latency-starved GEMMs), else 128x128.
struct GemmParams {
  const u16* A; long lda, sA1;
  const u16* B; long ldb;
  void* C;      long ldc, sC1;
  const float* bias;
  const float* resid; long ldr, sR1;
  float scale;
  int M, N, K;
};

template <bool OUTBF16, bool BIASV, bool RESID, bool GELU_, bool NT64>
__global__ __launch_bounds__(256) void gemm_k(GemmParams p) {
  constexpr int NJ = NT64 ? 2 : 4;
  __shared__ u16 As[4096];                   // 128 x 32
  __shared__ u16 Bs[NT64 ? 2048 : 4096];     // (64|128) x 32
  int tid = threadIdx.x;
  int z1 = blockIdx.z;
  const u16* A = p.A + (long)z1 * p.sA1;
  const u16* B = p.B;
  int m0 = blockIdx.y * 128, n0 = blockIdx.x * (NT64 ? 64 : 128);
  int wave = tid >> 6, lane = tid & 63;
  int quad = lane >> 4, lrow = lane & 15;
  int wm = (wave & 1) * 64;
  int wn = NT64 ? (wave >> 1) * 32 : (wave >> 1) * 64;

  int rA0 = m0 + (tid >> 2);        if (rA0 > p.M - 1) rA0 = p.M - 1;
  int rA1 = m0 + 64 + (tid >> 2);   if (rA1 > p.M - 1) rA1 = p.M - 1;
  int c8 = (tid & 3) << 3;
  const u16* pa0 = A + (long)rA0 * p.lda + c8;
  const u16* pa1 = A + (long)rA1 * p.lda + c8;
  u16* lA0 = As + wave * 512;  u16* lA1 = As + 2048 + wave * 512;

  const u16 *pb0, *pb1 = nullptr;
  u16 *lB0, *lB1 = nullptr;
  {
    int rB0 = n0 + (tid >> 2);
    if (!NT64) {
      int rB1 = n0 + 64 + (tid >> 2);
      if (rB0 > p.N - 1) rB0 = p.N - 1;
      if (rB1 > p.N - 1) rB1 = p.N - 1;
      pb1 = B + (long)rB1 * p.ldb + c8;
      lB1 = Bs + 2048 + wave * 512;
    }
    pb0 = B + (long)rB0 * p.ldb + c8;
    lB0 = Bs + wave * 512;
  }

  f32x4 acc[4][NJ];
#pragma unroll
  for (int i = 0; i < 4; i++)
#pragma unroll
    for (int j = 0; j < NJ; j++) acc[i][j] = (f32x4){0.f, 0.f, 0.f, 0.f};

  for (int k0 = 0; k0 < p.K; k0 += 32) {
    load_lds16(pa0 + k0, lA0, lane);
    load_lds16(pa1 + k0, lA1, lane);
    load_lds16(pb0 + k0, lB0, lane);
    if (!NT64) load_lds16(pb1 + k0, lB1, lane);
    __syncthreads();
    short8 af[4], bfr[NJ];
#pragma unroll
    for (int i = 0; i < 4; i++)  af[i]  = *(const short8*)&As[(wm + i * 16 + lrow) * 32 + quad * 8];
#pragma unroll
    for (int j = 0; j < NJ; j++) bfr[j] = *(const short8*)&Bs[(wn + j * 16 + lrow) * 32 + quad * 8];
#pragma unroll
    for (int i = 0; i < 4; i++)
#pragma unroll
      for (int j = 0; j < NJ; j++)
        acc[i][j] = __builtin_amdgcn_mfma_f32_16x16x32_bf16(af[i], bfr[j], acc[i][j], 0, 0, 0);
    __syncthreads();
  }

  float* Cf = (float*)p.C;
  u16*   Ch = (u16*)p.C;
  long cbase = (long)z1 * p.sC1;
#pragma unroll
  for (int i = 0; i < 4; i++) {
    int rbase = m0 + wm + i * 16 + quad * 4;
#pragma unroll
    for (int j = 0; j < NJ; j++) {
      int c = n0 + wn + j * 16 + lrow;
      if (c >= p.N) continue;
#pragma unroll
      for (int rr = 0; rr < 4; rr++) {
        int r = rbase + rr;
        if (r >= p.M) continue;
        float v = acc[i][j][rr] * p.scale;
        if (BIASV) v += p.bias[c];
        if (GELU_) v = 0.5f * v * (1.0f + erff(v * 0.70710678118654752f));
        if (RESID) v += p.resid[(long)z1 * p.sR1 + (long)r * p.ldr + c];
        long o = cbase + (long)r * p.ldc + c;
        if (OUTBF16) Ch[o] = f2bf(v);
        else         Cf[o] = v;
      }
    }
  }
}

// ---------------------------------------------------------------- temporal attention (T=4)
__global__ __launch_bounds__(64) void attn_t_k(const u16* __restrict__ qkv,
                                               u16* __restrict__ outb) {
  int h = blockIdx.x;
  int g = blockIdx.y;
  int d = threadIdx.x;
  long base = (long)g * 4 * 2304 + h * 64 + d;
  float q[4], k[4], vv[4];
#pragma unroll
  for (int t = 0; t < 4; t++) {
    q[t]  = bf2f(qkv[base + (long)t * 2304]);
    k[t]  = bf2f(qkv[base + (long)t * 2304 + 768]);
    vv[t] = bf2f(qkv[base + (long)t * 2304 + 1536]);
  }
  float sc[4][4];
#pragma unroll
  for (int i = 0; i < 4; i++)
#pragma unroll
    for (int j = 0; j < 4; j++) {
      float pv = q[i] * k[j];
#pragma unroll
      for (int m = 32; m; m >>= 1) pv += __shfl_xor(pv, m);
      sc[i][j] = pv * 0.125f;
    }
#pragma unroll
  for (int i = 0; i < 4; i++) {
    float mx = fmaxf(fmaxf(sc[i][0], sc[i][1]), fmaxf(sc[i][2], sc[i][3]));
    float e0 = __expf(sc[i][0] - mx), e1 = __expf(sc[i][1] - mx);
    float e2 = __expf(sc[i][2] - mx), e3 = __expf(sc[i][3] - mx);
    float inv = 1.0f / (e0 + e1 + e2 + e3);
    float ov = (e0 * vv[0] + e1 * vv[1] + e2 * vv[2] + e3 * vv[3]) * inv;
    outb[((long)g * 4 + i) * DIM + h * 64 + d] = f2bf(ov);
  }
}

// ---------------------------------------------------------------- geometry tables
__global__ void geo_pre_k(const float* __restrict__ wg_w,
                          const float* __restrict__ wg_b,
                          float* __restrict__ sxsyc) {
  int t = threadIdx.x;
  if (t >= 384) return;
  int h = t >> 5, dd = t & 31;
  float dx = logf(fmaxf((float)dd * (1.0f / 33.0f), 0.001f));
  float sx = 0.f, sy = 0.f;
#pragma unroll
  for (int k2 = 0; k2 < 8; k2++) {
    float dm = powf(1000.0f, -(float)k2 / 8.0f);
    float a = 100.0f * dx * dm;
    float sn = sinf(a), cs = cosf(a);
    sx += sn * wg_w[h * 64 + k2]     + cs * wg_w[h * 64 + 32 + k2];
    sy += sn * wg_w[h * 64 + 8 + k2] + cs * wg_w[h * 64 + 40 + k2];
  }
  sxsyc[t] = sx;
  sxsyc[384 + t] = sy;
  if (dd == 0) {
    float c = wg_b[h];
#pragma unroll
    for (int k2 = 48; k2 < 64; k2++) c += wg_w[h * 64 + k2];
    sxsyc[768 + h] = c;
  }
}

__global__ __launch_bounds__(256) void geo_bias_k(const float* __restrict__ sxsyc,
                                                  float* __restrict__ Bh_g) {
  int h = blockIdx.x / 4;
  int idx = (blockIdx.x % 4) * 256 + threadIdx.x;
  int dr = idx >> 5, dc = idx & 31;
  float v = sxsyc[h * 32 + dr] + sxsyc[384 + h * 32 + dc] + sxsyc[768 + h];
  Bh_g[h * 1024 + idx] = logf(fmaxf(fmaxf(v, 0.0f), 1e-6f));
}

// ---------------------------------------------------------------- V transpose to global Vt
__global__ __launch_bounds__(256) void vtrans_k(const u16* __restrict__ qkv_s,
                                                u16* __restrict__ Vt) {
  __shared__ u16 tile[64][33];
  int bh = blockIdx.y;
  int bt = bh / 12, h = bh % 12;
  int j0 = blockIdx.x * 32;
  int tid = threadIdx.x;
#pragma unroll
  for (int it = 0; it < 8; it++) {
    int jj = it * 4 + (tid >> 6);
    int d = tid & 63;
    int j = j0 + jj;
    u16 v = 0;
    if (j < NSP) v = qkv_s[((long)bt * NSP + j) * 2304 + 1536 + h * 64 + d];
    tile[d][jj] = v;
  }
  __syncthreads();
#pragma unroll
  for (int it = 0; it < 8; it++) {
    int d = it * 8 + (tid >> 5);
    int j = tid & 31;
    Vt[((long)bh * 64 + d) * VT_LD + j0 + j] = tile[d][j];
  }
}

// ---------------------------------------------------------------- fused spatial attention
// 1-D grid 1632: xcd-swizzled (bh grouped per XCD for K/V L2 locality).
// 17 K-tiles of 64 rows, K double-buffered (next tile issued at iter top), 1 barrier/iter.
__global__ __launch_bounds__(256, 4) void attn_s_k(const u16* __restrict__ qkv,
                                                   const u16* __restrict__ Vt,
                                                   const float* __restrict__ Bh_g,
                                                   u16* __restrict__ attn_o) {
  __shared__ u16 KsF[8192];     // 2 bufs x (64 rows x 64 cols as two 32-col subtiles)
  __shared__ u16 UN[4608];      // union: Q staging (2x2048) then P (64 x PS_LD)
  __shared__ float BhS[1024];
  const int bid = blockIdx.x;
  const int slot = bid >> 3;
  const int bh = (bid & 7) * 12 + slot / 17;
  const int qt = slot % 17;
  const int bt = bh / 12, h = bh % 12;
  const int tid = threadIdx.x;
  const int wave = tid >> 6, lane = tid & 63;
  const int quad = lane >> 4, lr = lane & 15;
  const int m0 = qt * 64;
  const long qb = (long)bt * NSP * 2304 + h * 64;

#pragma unroll
  for (int i = 0; i < 4; i++) BhS[tid + i * 256] = Bh_g[h * 1024 + tid + i * 256];

  const int rowq = tid >> 2, colq = (tid & 3) << 3;
  // stage Q (64x64) as 2 subtiles
  {
    int tokq = m0 + rowq; if (tokq > 1024) tokq = 1024;
    const u16* gq = qkv + qb + (long)tokq * 2304 + colq;
    load_lds16(gq,      UN + wave * 512, lane);
    load_lds16(gq + 32, UN + 2048 + wave * 512, lane);
  }
  // pre-issue K tile 0 into buf 0
  {
    int t0 = rowq; if (t0 > 1024) t0 = 1024;
    const u16* g0 = qkv + qb + 768 + (long)t0 * 2304 + colq;
    load_lds16(g0,      KsF + wave * 512, lane);
    load_lds16(g0 + 32, KsF + 2048 + wave * 512, lane);
  }
  __syncthreads();
  short8 qf[2];
#pragma unroll
  for (int ks = 0; ks < 2; ks++)
    qf[ks] = *(const short8*)&UN[ks * 2048 + (wave * 16 + lr) * 32 + quad * 8];

  f32x4 Oa[4];
  float mr[4], lsum[4];
#pragma unroll
  for (int n = 0; n < 4; n++) Oa[n] = (f32x4){0.f, 0.f, 0.f, 0.f};
#pragma unroll
  for (int r = 0; r < 4; r++) { mr[r] = -1e30f; lsum[r] = 0.f; }

  int rid[4], ri_[4], ci_[4];
  float rok[4];
#pragma unroll
  for (int r = 0; r < 4; r++) {
    int i0 = m0 + wave * 16 + quad * 4 + r;
    rid[r] = i0;
    int ii = i0 < NSP ? i0 : (NSP - 1);
    int im1 = ii > 0 ? ii - 1 : 0;
    ri_[r] = im1 >> 5;
    ci_[r] = im1 & 31;
    rok[r] = (i0 > 0) ? 1.0f : 0.0f;
  }

  const u16* vrow = Vt + ((long)bh * 64 + lr) * VT_LD;   // + n*16*VT_LD per frag

  for (int kt = 0; kt < 17; kt++) {
    const int cur = kt & 1, nxt = cur ^ 1;
    // issue next K tile (covered by this iteration's compute; drained at end barrier)
    if (kt < 16) {
      int t0 = (kt + 1) * 64 + rowq; if (t0 > 1024) t0 = 1024;
      const u16* g0 = qkv + qb + 768 + (long)t0 * 2304 + colq;
      load_lds16(g0,      KsF + nxt * 4096 + wave * 512, lane);
      load_lds16(g0 + 32, KsF + nxt * 4096 + 2048 + wave * 512, lane);
    }
    // prefetch V (ks=0 half) into regs
    short8 vf0[4], vf1[4];
#pragma unroll
    for (int n = 0; n < 4; n++)
      vf0[n] = *(const short8*)(vrow + (long)n * 16 * VT_LD + kt * 64 + quad * 8);
    // S strip = Q(16) K^T(64)
    f32x4 sa[4];
#pragma unroll
    for (int j = 0; j < 4; j++) sa[j] = (f32x4){0.f, 0.f, 0.f, 0.f};
#pragma unroll
    for (int ks = 0; ks < 2; ks++) {
#pragma unroll
      for (int j = 0; j < 4; j++) {
        short8 kf = *(const short8*)&KsF[cur * 4096 + ks * 2048 + (j * 16 + lr) * 32 + quad * 8];
        sa[j] = __builtin_amdgcn_mfma_f32_16x16x32_bf16(qf[ks], kf, sa[j], 0, 0, 0);
      }
    }
    // prefetch V (ks=1 half)
#pragma unroll
    for (int n = 0; n < 4; n++)
      vf1[n] = *(const short8*)(vrow + (long)n * 16 * VT_LD + kt * 64 + 32 + quad * 8);
    // scale + geometric bias + column mask
#pragma unroll
    for (int j = 0; j < 4; j++) {
      int j0 = kt * 64 + j * 16 + lr;
      bool jv = j0 < NSP;
      int jm1 = j0 > 0 ? j0 - 1 : 0;
      if (jm1 > 1023) jm1 = 1023;
      int rj = jm1 >> 5, cj = jm1 & 31;
      float jnz = (j0 > 0) ? 1.0f : 0.0f;
#pragma unroll
      for (int r = 0; r < 4; r++) {
        int ad = ri_[r] - rj; ad = ad < 0 ? -ad : ad;
        int cd = ci_[r] - cj; cd = cd < 0 ? -cd : cd;
        float sv = sa[j][r] * 0.125f + BhS[ad * 32 + cd] * jnz * rok[r];
        sa[j][r] = jv ? sv : -1e30f;
      }
    }
    // online softmax; P -> LDS (wave-private rows, no barrier needed)
    float alpha[4];
#pragma unroll
    for (int r = 0; r < 4; r++) {
      float tm = fmaxf(fmaxf(sa[0][r], sa[1][r]), fmaxf(sa[2][r], sa[3][r]));
      tm = fmaxf(tm, __shfl_xor(tm, 1));
      tm = fmaxf(tm, __shfl_xor(tm, 2));
      tm = fmaxf(tm, __shfl_xor(tm, 4));
      tm = fmaxf(tm, __shfl_xor(tm, 8));
      float mn = fmaxf(mr[r], tm);
      float a = __expf(mr[r] - mn);
      alpha[r] = a;
      float ls = 0.f;
      int prow = (wave * 16 + quad * 4 + r) * PS_LD;
#pragma unroll
      for (int j = 0; j < 4; j++) {
        float pp = __expf(sa[j][r] - mn);
        ls += pp;
        UN[prow + j * 16 + lr] = f2bf(pp);
      }
      lsum[r] = lsum[r] * a + ls;
      mr[r] = mn;
    }
#pragma unroll
    for (int n = 0; n < 4; n++)
#pragma unroll
      for (int r = 0; r < 4; r++) Oa[n][r] *= alpha[r];
    // O += P V
#pragma unroll
    for (int ks = 0; ks < 2; ks++) {
      short8 pf = *(const short8*)&UN[(wave * 16 + lr) * PS_LD + ks * 32 + quad * 8];
#pragma unroll
      for (int n = 0; n < 4; n++)
        Oa[n] = __builtin_amdgcn_mfma_f32_16x16x32_bf16(pf, ks ? vf1[n] : vf0[n], Oa[n], 0, 0, 0);
    }
    __syncthreads();   // drains next-K loads; separates P/K-buf generations
  }
  // finalize
#pragma unroll
  for (int r = 0; r < 4; r++) {
    float l = lsum[r];
    l += __shfl_xor(l, 1);
    l += __shfl_xor(l, 2);
    l += __shfl_xor(l, 4);
    l += __shfl_xor(l, 8);
    lsum[r] = 1.0f / l;
  }
#pragma unroll
  for (int r = 0; r < 4; r++) {
    int i0 = rid[r];
    if (i0 < NSP) {
      long ob = ((long)bt * NSP + i0) * 768 + h * 64;
#pragma unroll
      for (int n = 0; n < 4; n++)
        attn_o[ob + n * 16 + lr] = f2bf(Oa[n][r] * lsum[r]);
    }
  }
}

// ---------------------------------------------------------------- assemble xout_pre + fused LN2
__global__ __launch_bounds__(256) void assemble_ln_k(const float* __restrict__ x,
                                                     const float* __restrict__ xt,
                                                     const float* __restrict__ res_s,
                                                     const float* __restrict__ g,
                                                     const float* __restrict__ b,
                                                     float* __restrict__ outp,
                                                     u16* __restrict__ ln2b) {
  int n = blockIdx.x, bb = blockIdx.y;
  int tid = threadIdx.x;
  long ob = ((long)bb * 4097 + n) * DIM;
  float val[3];
  if (n == 0) {
#pragma unroll
    for (int i = 0; i < 3; i++) {
      int c = tid + i * 256;
      float acc = x[ob + c];
#pragma unroll
      for (int t = 0; t < 4; t++)
        acc += 0.25f * res_s[((long)(bb * 4 + t) * NSP) * DIM + c];
      val[i] = acc;
    }
  } else {
    int q = n - 1, hw = q >> 2, t = q & 3;
    long rs = ((long)(bb * 4 + t) * NSP + 1 + hw) * DIM;
    long xb = ((long)bb * 4096 + q) * DIM;
#pragma unroll
    for (int i = 0; i < 3; i++) {
      int c = tid + i * 256;
      val[i] = xt[xb + c] + res_s[rs + c];
    }
  }
  float s = 0.f, ss = 0.f;
#pragma unroll
  for (int i = 0; i < 3; i++) {
    outp[ob + tid + i * 256] = val[i];
    s += val[i];
    ss += val[i] * val[i];
  }
  __shared__ float red[8];
#pragma unroll
  for (int m = 32; m; m >>= 1) {
    s  += __shfl_xor(s, m);
    ss += __shfl_xor(ss, m);
  }
  int wid = tid >> 6;
  if ((tid & 63) == 0) { red[wid] = s; red[4 + wid] = ss; }
  __syncthreads();
  s  = red[0] + red[1] + red[2] + red[3];
  ss = red[4] + red[5] + red[6] + red[7];
  float mean = s * (1.0f / 768.0f);
  float var  = ss * (1.0f / 768.0f) - mean * mean;
  float rs = rsqrtf(var + 1e-5f);
#pragma unroll
  for (int i = 0; i < 3; i++) {
    int c = tid + i * 256;
    ln2b[ob + c] = f2bf((val[i] - mean) * rs * g[c] + b[c]);
  }
}

// ================================================================ host
extern "C" void kernel_launch(void* const* d_in, const int* in_sizes, int n_in,
                              void* d_out, int out_size, void* d_ws, size_t ws_size,
                              hipStream_t stream) {
  const float* x        = (const float*)d_in[0];
  const float* norm1_g  = (const float*)d_in[1];
  const float* norm1_b  = (const float*)d_in[2];
  const float* qkv_w    = (const float*)d_in[3];
  const float* proj_w   = (const float*)d_in[4];
  const float* proj_b   = (const float*)d_in[5];
  const float* wg_w     = (const float*)d_in[6];
  const float* wg_b     = (const float*)d_in[7];
  const float* tnorm1_g = (const float*)d_in[8];
  const float* tnorm1_b = (const float*)d_in[9];
  const float* tqkv_w   = (const float*)d_in[10];
  const float* tproj_w  = (const float*)d_in[11];
  const float* tproj_b  = (const float*)d_in[12];
  const float* tfc_w    = (const float*)d_in[13];
  const float* tfc_b    = (const float*)d_in[14];
  const float* norm2_g  = (const float*)d_in[15];
  const float* norm2_b  = (const float*)d_in[16];
  const float* fc1_w    = (const float*)d_in[17];
  const float* fc1_b    = (const float*)d_in[18];
  const float* fc2_w    = (const float*)d_in[19];
  const float* fc2_b    = (const float*)d_in[20];
  float* out = (float*)d_out;
  (void)in_sizes; (void)n_in; (void)out_size;

  char* base = (char*)d_ws;
  size_t off = 0;
  auto take = [&](size_t bytes) -> char* {
    char* p = base + off;
    off += (bytes + 255) & ~(size_t)255;
    return p;
  };

  // persistent
  u16* wb_tqkv = (u16*)take(2304LL * 768 * 2);
  u16* wb_tprj = (u16*)take(768LL * 768 * 2);
  u16* wb_tfc  = (u16*)take(768LL * 768 * 2);
  u16* wb_qkv  = (u16*)take(2304LL * 768 * 2);
  u16* wb_proj = (u16*)take(768LL * 768 * 2);
  u16* wb_fc1  = (u16*)take(3072LL * 768 * 2);
  u16* wb_fc2  = (u16*)take(3072LL * 768 * 2);
  float* xt_f  = (float*)take(8192LL * 768 * 4);
  float* sxsyc = (float*)take(4096);
  float* Bh_g  = (float*)take(12LL * 1024 * 4);
  char* pool   = take(64536576);
  size_t REQ = off;

  // phase T (temporal)
  u16* qkv_t  = (u16*)(pool);                  // 37,748,736
  u16* ln_xt  = (u16*)(pool + 37748736);       // 12,582,912
  u16* attn_t = ln_xt;
  u16* h1     = (u16*)(pool + 50331648);       // 12,582,912
  // phase S (spatial)
  u16* qkv_s  = (u16*)(pool);                  // 37,785,600
  u16* ln_xs  = (u16*)(pool + 37785600);       // 12,595,200
  u16* attn_sp = ln_xs;
  u16* Vt     = (u16*)(pool + 50380800);       // 14,155,776
  // assemble phase: ln2b (pool+0, 12.6MB) and res_s MUST be disjoint —
  // res_s lives at pool+12,585,984 (25.2MB, ends 37.78MB, before attn_sp). [R4 bug fix]
  u16* ln2b   = (u16*)(pool);                  // 12,585,984
  float* res_s = (float*)(pool + 12585984);    // 25,190,400 (over dead qkv_s tail)
  // phase M (MLP): geluh may overlap res_s (dead) but not ln2b.
  u16* geluh  = (u16*)(pool + 12585984);       // 50,343,936 (ends 62,929,920)

  if (ws_size < REQ) {   // diagnosable fallback
    long n = 2LL * 4097 * 768;
    zero_k<<<dim3((n + 255) / 256), 256, 0, stream>>>(out, n);
    return;
  }

  // ---- weights -> bf16
  {
    struct { const float* s; u16* d; long n; } cv[7] = {
      {tqkv_w, wb_tqkv, 2304LL * 768}, {tproj_w, wb_tprj, 768LL * 768},
      {tfc_w, wb_tfc, 768LL * 768},    {qkv_w, wb_qkv, 2304LL * 768},
      {proj_w, wb_proj, 768LL * 768},  {fc1_w, wb_fc1, 3072LL * 768},
      {fc2_w, wb_fc2, 3072LL * 768}};
    for (int i = 0; i < 7; i++)
      cvt_k<<<dim3((cv[i].n + 255) / 256), 256, 0, stream>>>(cv[i].s, cv[i].d, cv[i].n);
  }
  geo_pre_k<<<1, 384, 0, stream>>>(wg_w, wg_b, sxsyc);
  geo_bias_k<<<48, 256, 0, stream>>>(sxsyc, Bh_g);

  // ---- temporal branch
  ln_xt_k<<<dim3(4096, 2), 256, 0, stream>>>(x, tnorm1_g, tnorm1_b, ln_xt);
  {
    GemmParams p{};
    p.A = ln_xt; p.lda = 768; p.B = wb_tqkv; p.ldb = 768;
    p.C = qkv_t; p.ldc = 2304; p.scale = 1.0f;
    p.M = 8192; p.N = 2304; p.K = 768;
    gemm_k<true, false, false, false, false><<<dim3(18, 64, 1), 256, 0, stream>>>(p);
  }
  attn_t_k<<<dim3(12, 2048), 64, 0, stream>>>(qkv_t, attn_t);
  {
    GemmParams p{};
    p.A = attn_t; p.lda = 768; p.B = wb_tprj; p.ldb = 768;
    p.C = h1; p.ldc = 768; p.bias = tproj_b; p.scale = 1.0f;
    p.M = 8192; p.N = 768; p.K = 768;
    gemm_k<true, true, false, false, true><<<dim3(12, 64, 1), 256, 0, stream>>>(p);
  }
  {
    GemmParams p{};
    p.A = h1; p.lda = 768; p.sA1 = 4096LL * 768;
    p.B = wb_tfc; p.ldb = 768;
    p.C = xt_f; p.ldc = 768; p.sC1 = 4096LL * 768;
    p.bias = tfc_b;
    p.resid = x + 768; p.ldr = 768; p.sR1 = 4097LL * 768;
    p.scale = 1.0f;
    p.M = 4096; p.N = 768; p.K = 768;
    gemm_k<false, true, true, false, true><<<dim3(12, 32, 2), 256, 0, stream>>>(p);
  }

  // ---- spatial branch
  ln_xs_k<<<dim3(NSP, 8), 256, 0, stream>>>(x, xt_f, norm1_g, norm1_b, ln_xs);
  {
    GemmParams p{};
    p.A = ln_xs; p.lda = 768; p.B = wb_qkv; p.ldb = 768;
    p.C = qkv_s; p.ldc = 2304; p.scale = 1.0f;
    p.M = 8200; p.N = 2304; p.K = 768;
    gemm_k<true, false, false, false, false><<<dim3(18, 65, 1), 256, 0, stream>>>(p);
  }
  vtrans_k<<<dim3(36, 96), 256, 0, stream>>>(qkv_s, Vt);
  attn_s_k<<<dim3(1632), 256, 0, stream>>>(qkv_s, Vt, Bh_g, attn_sp);
  {
    GemmParams p{};
    p.A = attn_sp; p.lda = 768; p.B = wb_proj; p.ldb = 768;
    p.C = res_s; p.ldc = 768; p.bias = proj_b; p.scale = 1.0f;
    p.M = 8200; p.N = 768; p.K = 768;
    gemm_k<false, true, false, false, true><<<dim3(12, 65, 1), 256, 0, stream>>>(p);
  }
  assemble_ln_k<<<dim3(4097, 2), 256, 0, stream>>>(x, xt_f, res_s, norm2_g, norm2_b, out, ln2b);

  // ---- MLP
  {
    GemmParams p{};
    p.A = ln2b; p.lda = 768; p.B = wb_fc1; p.ldb = 768;
    p.C = geluh; p.ldc = 3072; p.bias = fc1_b; p.scale = 1.0f;
    p.M = 8194; p.N = 3072; p.K = 768;
    gemm_k<true, true, false, true, false><<<dim3(24, 65, 1), 256, 0, stream>>>(p);
  }
  {
    GemmParams p{};
    p.A = geluh; p.lda = 3072; p.B = wb_fc2; p.ldb = 3072;
    p.C = out; p.ldc = 768; p.bias = fc2_b;
    p.resid = out; p.ldr = 768; p.scale = 1.0f;
    p.M = 8194; p.N = 768; p.K = 3072;
    gemm_k<false, true, true, false, true><<<dim3(12, 65, 1), 256, 0, stream>>>(p);
  }
}